// Round 1
// baseline (340.844 us; speedup 1.0000x reference)
//
#include <hip/hip_runtime.h>
#include <hip/hip_bf16.h>
#include <stdint.h>

// Problem: B=8, N=8192, C=256, H=8, D=32, P=64, F=4C=1024
// qkvv layout: [part(4)][b(8)][h*32+d(256)][n(8192)] bf16, n contiguous.
// Inputs self-detected as fp32-or-bf16. x is converted to bf16 INSIDE k_qkvv
// (no separate convert kernel); weights canonicalized by k_convert_w.
// k_qkvv v2: 1024 blocks x (64 tokens x ALL 1024 f). x tile staged once into
// swizzled LDS (single barrier per block); Wq A-frags read straight from L2;
// per-wave LDS-transpose epilogue -> 64B-contiguous qkvv stores; per-wave
// L2-norm partials. K-loop LDS tiles elsewhere keep XOR chunk swizzle.

typedef __attribute__((ext_vector_type(8))) __bf16 bf16x8;
typedef __attribute__((ext_vector_type(4))) __bf16 bf16x4;
typedef __attribute__((ext_vector_type(4))) float f32x4;

#define MFMA(a, b, c) __builtin_amdgcn_mfma_f32_16x16x32_bf16((a), (b), (c), 0, 0, 0)

__device__ __forceinline__ void gl2lds16(const __bf16* g, __bf16* l) {
  __builtin_amdgcn_global_load_lds(
      (const __attribute__((address_space(1))) void*)(const void*)g,
      (__attribute__((address_space(3))) void*)(void*)l, 16, 0, 0);
}

// Self-detect: sample x's first 64 dwords (uniform scalar loads). fp32 data's
// low halfwords are mantissa bytes -> exponent field >= 0xC0 w.p. ~1/4; real
// bf16 N(0,1)-scale data never has exp >= 0xC0.
__device__ __forceinline__ int detect_f32(const unsigned int* __restrict__ xw) {
  int c = 0;
#pragma unroll
  for (int i = 0; i < 64; ++i) {
    const unsigned int u = xw[i];
    c += (((u >> 7) & 0xFF) >= 0xC0) ? 1 : 0;
    c += (((u >> 23) & 0xFF) >= 0xC0) ? 1 : 0;
  }
  return c > 8;
}

// ---------------- K0b: canonicalize the 11 weight/bias/temp inputs -----------
__global__ __launch_bounds__(256) void k_convert_w(
    const void* s0, const void* s1, const void* s2, const void* s3, const void* s4,
    const void* s5, const void* s6, const void* s7, const void* s8, const void* s9,
    const void* s10, __bf16* __restrict__ cw, const void* __restrict__ xsrc) {
  const int i = (blockIdx.x * 256 + threadIdx.x) * 8;
  if (i >= 1376656) return;
  const void* s;
  int base;
  if (i < 262144)        { s = s0;  base = 0; }
  else if (i < 786432)   { s = s1;  base = 262144; }
  else if (i < 786496)   { s = s2;  base = 786432; }
  else if (i < 1310784)  { s = s3;  base = 786496; }
  else if (i < 1310848)  { s = s4;  base = 1310784; }
  else if (i < 1343616)  { s = s5;  base = 1310848; }
  else if (i < 1343744)  { s = s6;  base = 1343616; }
  else if (i < 1376512)  { s = s7;  base = 1343744; }
  else if (i < 1376640)  { s = s8;  base = 1376512; }
  else if (i < 1376648)  { s = s9;  base = 1376640; }
  else                   { s = s10; base = 1376648; }
  const int li = i - base;
  if (detect_f32((const unsigned int*)xsrc)) {
    const float* sf = (const float*)s;
#pragma unroll
    for (int j = 0; j < 8; ++j) cw[i + j] = (__bf16)sf[li + j];
  } else {
    const __bf16* sb = (const __bf16*)s;
#pragma unroll
    for (int j = 0; j < 8; ++j) cw[i + j] = sb[li + j];
  }
}

// ---------------- K1: qkvv = x @ Wqkvv^T (v2: one barrier, all-f per block) --
__global__ __launch_bounds__(256, 3) void k_qkvv(const void* __restrict__ xsrc,
                                                 const __bf16* __restrict__ Wq,
                                                 __bf16* __restrict__ qkvv,
                                                 float* __restrict__ npart) {
  __shared__ alignas(16) __bf16 Xs[64 * 256];     // 32 KB, 16B-chunk XOR swizzle
  __shared__ alignas(16) __bf16 Csw[4][16][72];   // per-wave transpose slab, 9 KB
  const int t = threadIdx.x;
  const int tile = blockIdx.x;                    // 0..1023
  const int b = tile >> 7;
  const int n0 = (tile & 127) * 64;
  const int r = t >> 2, q4 = t & 3;               // stage: 4 threads per row
  // ---- stage x tile [64 n][256 k] -> bf16 LDS (chunk c stored at c^(r&7))
  if (detect_f32((const unsigned int*)xsrc)) {
    const float* xf = (const float*)xsrc + (size_t)(b * 8192 + n0 + r) * 256;
#pragma unroll
    for (int p = 0; p < 8; ++p) {
      const int c = q4 + p * 4;                   // logical 8-elem chunk
      const f32x4 a = *(const f32x4*)(xf + c * 8);
      const f32x4 a2 = *(const f32x4*)(xf + c * 8 + 4);
      bf16x8 v;
#pragma unroll
      for (int j = 0; j < 4; ++j) { v[j] = (__bf16)a[j]; v[4 + j] = (__bf16)a2[j]; }
      *(bf16x8*)(Xs + r * 256 + ((c ^ (r & 7)) * 8)) = v;
    }
  } else {
    const __bf16* xb = (const __bf16*)xsrc + (size_t)(b * 8192 + n0 + r) * 256;
#pragma unroll
    for (int p = 0; p < 8; ++p) {
      const int c = q4 + p * 4;
      *(bf16x8*)(Xs + r * 256 + ((c ^ (r & 7)) * 8)) = *(const bf16x8*)(xb + c * 8);
    }
  }
  __syncthreads();  // the ONLY block-wide barrier
  const int lane = t & 63, w = t >> 6;
  const int l15 = lane & 15, g = lane >> 4;
  const int sw = l15 & 7;
  for (int ft = 0; ft < 4; ++ft) {
    const int f1 = w * 256 + ft * 64;             // wave-private f panel
    f32x4 acc[4][4] = {};
#pragma unroll
    for (int k0 = 0; k0 < 256; k0 += 32) {
      bf16x8 af[4], bfr[4];
#pragma unroll
      for (int i = 0; i < 4; ++i)   // Wq rows straight from L2 (64B/row/instr)
        af[i] = *(const bf16x8*)(Wq + (size_t)(f1 + i * 16 + l15) * 256 + k0 + g * 8);
#pragma unroll
      for (int j = 0; j < 4; ++j)   // x frags from swizzled LDS
        bfr[j] = *(const bf16x8*)(Xs + (j * 16 + l15) * 256 + ((((k0 >> 3) + g) ^ sw) * 8));
#pragma unroll
      for (int i = 0; i < 4; ++i)
#pragma unroll
        for (int j = 0; j < 4; ++j) acc[i][j] = MFMA(af[i], bfr[j], acc[i][j]);
    }
    // ---- epilogue: norm partials (q/k panels) + per-wave transpose + store
#pragma unroll
    for (int i = 0; i < 4; ++i) {
      if (f1 < 512) {  // q (f<256) and k (256<=f<512) L2-norm partial sums
#pragma unroll
        for (int rr = 0; rr < 4; ++rr) {
          float s = 0.f;
#pragma unroll
          for (int j = 0; j < 4; ++j) { const float v = acc[i][j][rr]; s += v * v; }
#pragma unroll
          for (int off = 1; off < 16; off <<= 1) s += __shfl_xor(s, off, 16);
          if (l15 == 0) npart[(size_t)tile * 512 + f1 + i * 16 + g * 4 + rr] = s;
        }
      }
#pragma unroll
      for (int j = 0; j < 4; ++j)
#pragma unroll
        for (int rr = 0; rr < 4; ++rr)
          Csw[w][g * 4 + rr][j * 16 + l15] = (__bf16)acc[i][j][rr];
      // wave-local LDS transpose readback (same-wave dep -> lgkmcnt only)
      const int f = f1 + i * 16 + l15;
      __bf16* dst = qkvv + (size_t)(((f >> 8) * 8 + b) * 256 + (f & 255)) * 8192 + n0;
#pragma unroll
      for (int h = 0; h < 2; ++h)
        *(bf16x8*)(dst + (h * 4 + g) * 8) = *(const bf16x8*)(&Csw[w][l15][(h * 4 + g) * 8]);
    }
  }
}

// ---------------- K1b: reduce norm partials over the 128 token-blocks of each b
__global__ __launch_bounds__(256) void k_nred(const float* __restrict__ npart,
                                              float* __restrict__ qsum,
                                              float* __restrict__ ksum) {
  const int which = blockIdx.x >> 3, b = blockIdx.x & 7;
  const int c = threadIdx.x;
  float s = 0.f;
#pragma unroll 4
  for (int j = 0; j < 128; ++j)
    s += npart[(size_t)(b * 128 + j) * 512 + which * 256 + c];
  (which ? ksum : qsum)[b * 256 + c] = s;
}

// ---------------- K3: k_proj / v_proj partial GEMMs (K-split) ----------------
__global__ __launch_bounds__(256) void k_proj_part(const __bf16* __restrict__ qkvv,
                                                   const __bf16* __restrict__ WE,
                                                   const __bf16* __restrict__ WF,
                                                   float* __restrict__ pbuf) {
  __shared__ alignas(16) __bf16 As[128 * 32];
  __shared__ alignas(16) __bf16 Bs[64 * 32];
  const int t = threadIdx.x, lane = t & 63;
  const int wr = t >> 7, wc = (t >> 6) & 1;
  const int l15 = lane & 15, g = lane >> 4;
  const int kc = blockIdx.x, mt = blockIdx.y, pj = blockIdx.z;
  const __bf16* A = qkvv + (size_t)(pj ? 3 : 1) * 2048 * 8192;
  const __bf16* Bm = pj ? WF : WE;
  const int r0 = mt * 128;
  f32x4 acc[4][2] = {};
  const int r = t >> 2;
  const int c8 = ((t & 3) ^ ((t >> 3) & 3)) * 8;
  const int cx = ((g ^ ((l15 >> 1) & 3)) * 8);
  for (int k0 = kc * 512; k0 < kc * 512 + 512; k0 += 32) {
#pragma unroll
    for (int i = 0; i < 2; ++i)
      gl2lds16(A + (size_t)(r0 + i * 64 + r) * 8192 + k0 + c8, As + i * 2048 + t * 8);
    gl2lds16(Bm + (size_t)r * 8192 + k0 + c8, Bs + t * 8);
    __syncthreads();
    bf16x8 af[4], bfr[2];
#pragma unroll
    for (int i = 0; i < 4; ++i)
      af[i] = *(const bf16x8*)(As + (wr * 64 + i * 16 + l15) * 32 + cx);
#pragma unroll
    for (int j = 0; j < 2; ++j)
      bfr[j] = *(const bf16x8*)(Bs + (wc * 32 + j * 16 + l15) * 32 + cx);
#pragma unroll
    for (int i = 0; i < 4; ++i)
#pragma unroll
      for (int j = 0; j < 2; ++j) acc[i][j] = MFMA(af[i], bfr[j], acc[i][j]);
    __syncthreads();
  }
  float* dst = pbuf + (size_t)((pj * 16 + kc) * 2048 + r0) * 64;
#pragma unroll
  for (int i = 0; i < 4; ++i)
#pragma unroll
    for (int j = 0; j < 2; ++j)
#pragma unroll
      for (int rr = 0; rr < 4; ++rr)
        dst[(wr * 64 + i * 16 + g * 4 + rr) * 64 + wc * 32 + j * 16 + l15] = acc[i][j][rr];
}

// ---------------- K3b: reduce + bias; emit bf16 MFMA-operand copies ----------
__global__ __launch_bounds__(256) void k_proj_reduce(const float* __restrict__ pbuf,
                                                     const __bf16* __restrict__ bE,
                                                     const __bf16* __restrict__ bF,
                                                     const float* __restrict__ qsum,
                                                     const __bf16* __restrict__ t2,
                                                     __bf16* __restrict__ kprojT,
                                                     __bf16* __restrict__ vprojb) {
  const int idx = blockIdx.x * 256 + threadIdx.x;  // [0, 262144)
  const int pj = idx >> 17, rp = idx & 131071, p = idx & 63;
  const int row = rp >> 6, bh = row >> 5, d = row & 31, h = bh & 7;
  float s = (float)((pj ? bF : bE)[p]);
  const float* src = pbuf + (size_t)pj * 16 * 131072 + rp;
#pragma unroll
  for (int k = 0; k < 16; ++k) s += src[(size_t)k * 131072];
  if (pj == 0) {
    const float qi = 1.0f / fmaxf(sqrtf(qsum[row]), 1e-12f);
    kprojT[bh * 2048 + p * 32 + d] = (__bf16)(s * qi * (float)t2[h]);
  } else {
    vprojb[bh * 2048 + d * 64 + p] = (__bf16)s;
  }
}

// ---------------- K4a: S[d,e] = q . k partials (K-split 8 x 4 waves) ---------
__global__ __launch_bounds__(256) void k_sca_part(const __bf16* __restrict__ qkvv,
                                                  float* __restrict__ spart) {
  const int bh = blockIdx.x, kc = blockIdx.y;
  const int t = threadIdx.x, lane = t & 63, w = t >> 6;
  const __bf16* qb = qkvv + (size_t)(bh * 32) * 8192;
  const __bf16* kb = qkvv + (size_t)(2048 + bh * 32) * 8192;
  f32x4 acc[2][2] = {};
  const int kbase = kc * 1024 + w * 256 + (lane >> 4) * 8;
#pragma unroll
  for (int ks = 0; ks < 256; ks += 32) {
    bf16x8 af[2], bfr[2];
#pragma unroll
    for (int i = 0; i < 2; ++i) {
      af[i] = *(const bf16x8*)(qb + (size_t)(i * 16 + (lane & 15)) * 8192 + kbase + ks);
      bfr[i] = *(const bf16x8*)(kb + (size_t)(i * 16 + (lane & 15)) * 8192 + kbase + ks);
    }
#pragma unroll
    for (int i = 0; i < 2; ++i)
#pragma unroll
      for (int j = 0; j < 2; ++j) acc[i][j] = MFMA(af[i], bfr[j], acc[i][j]);
  }
  float* dst = spart + (size_t)((bh * 8 + kc) * 4 + w) * 1024;
#pragma unroll
  for (int i = 0; i < 2; ++i)
#pragma unroll
    for (int j = 0; j < 2; ++j)
#pragma unroll
      for (int rr = 0; rr < 4; ++rr)
        dst[(i * 16 + (lane >> 4) * 4 + rr) * 32 + j * 16 + (lane & 15)] = acc[i][j][rr];
}

// ---------------- K4b: reduce, scale, softmax over e; emit bf16 attn [d][e] --
__global__ __launch_bounds__(256) void k_sca_softmax(const float* __restrict__ spart,
                                                     const float* __restrict__ qsum,
                                                     const float* __restrict__ ksum,
                                                     const __bf16* __restrict__ temp1,
                                                     __bf16* __restrict__ attnb) {
  const int bh = blockIdx.x;
  __shared__ float S[1024];
  const int t = threadIdx.x;
  const float tmp = (float)temp1[bh & 7];
  for (int idx = t; idx < 1024; idx += 256) {
    float s = 0.f;
    const float* src = spart + (size_t)bh * 32768 + idx;
#pragma unroll
    for (int k = 0; k < 32; ++k) s += src[k * 1024];
    const float qi = 1.0f / fmaxf(sqrtf(qsum[bh * 32 + (idx >> 5)]), 1e-12f);
    const float ki = 1.0f / fmaxf(sqrtf(ksum[bh * 32 + (idx & 31)]), 1e-12f);
    S[idx] = s * qi * ki * tmp;
  }
  __syncthreads();
  const int lane = t & 63, w = t >> 6;
#pragma unroll
  for (int rr = 0; rr < 4; ++rr) {
    const int row = rr * 8 + w * 2 + (lane >> 5);
    const int e = lane & 31;
    float v = S[row * 32 + e];
    float m = v;
#pragma unroll
    for (int off = 16; off; off >>= 1) m = fmaxf(m, __shfl_xor(m, off, 32));
    const float ex = __expf(v - m);
    float sm = ex;
#pragma unroll
    for (int off = 16; off; off >>= 1) sm += __shfl_xor(sm, off, 32);
    attnb[(size_t)bh * 1024 + row * 32 + e] = (__bf16)(ex / sm);
  }
}

// ---------------- K4c/K5 merged: channel-attn apply + spatial attention ------
__global__ __launch_bounds__(256) void k_casa(const __bf16* __restrict__ qkvv,
                                              const __bf16* __restrict__ attnb,
                                              const __bf16* __restrict__ kprojT,
                                              const __bf16* __restrict__ vprojb,
                                              __bf16* __restrict__ xca,
                                              __bf16* __restrict__ xsa) {
  __shared__ __bf16 P[4][16 * 72];  // used by the sa branch only
  const int t = threadIdx.x, lane = t & 63, w = t >> 6;
  const int l15 = lane & 15, g = lane >> 4;
  if (blockIdx.y < 64) {
    // ---- channel attention: x_ca[d][tok] = sum_e attn[d][e] * v_ca[e][tok]
    const int bh = blockIdx.y, b = bh >> 3, h = bh & 7;
    const __bf16* vb = qkvv + (size_t)(4096 + bh * 32) * 8192;
    bf16x8 aa[2];
#pragma unroll
    for (int mi = 0; mi < 2; ++mi)
      aa[mi] = *(const bf16x8*)(attnb + bh * 1024 + (mi * 16 + l15) * 32 + g * 8);
#pragma unroll
    for (int it = 0; it < 4; ++it) {
      const int n = blockIdx.x * 256 + it * 64 + w * 16 + l15;
      union { bf16x8 v; unsigned short u[8]; } bq;
#pragma unroll
      for (int j = 0; j < 8; ++j)
        bq.u[j] = *(const unsigned short*)(vb + (size_t)(g * 8 + j) * 8192 + n);
      f32x4 o[2] = {};
#pragma unroll
      for (int mi = 0; mi < 2; ++mi) o[mi] = MFMA(aa[mi], bq.v, o[mi]);
#pragma unroll
      for (int mi = 0; mi < 2; ++mi) {
        bf16x4 p4;
#pragma unroll
        for (int rr = 0; rr < 4; ++rr) p4[rr] = (__bf16)o[mi][rr];
        *(bf16x4*)(xca + (size_t)(b * 8192 + n) * 256 + h * 32 + mi * 16 + g * 4) = p4;
      }
    }
  } else {
    // ---- spatial (low-rank) attention
    const int bh = blockIdx.y - 64;
    const __bf16* qb = qkvv + (size_t)(bh * 32) * 8192;
    bf16x8 ka[4], va[2][2];
#pragma unroll
    for (int tile = 0; tile < 4; ++tile)
      ka[tile] = *(const bf16x8*)(kprojT + bh * 2048 + (tile * 16 + l15) * 32 + g * 8);
#pragma unroll
    for (int mi = 0; mi < 2; ++mi)
#pragma unroll
      for (int kh = 0; kh < 2; ++kh)
        va[mi][kh] = *(const bf16x8*)(vprojb + bh * 2048 + (mi * 16 + l15) * 64 + kh * 32 + g * 8);
    __bf16* Pw = &P[w][0];
#pragma unroll
    for (int it = 0; it < 4; ++it) {
      const int n0 = blockIdx.x * 256 + it * 64 + w * 16;
      union { bf16x8 v; unsigned short u[8]; } bq;
#pragma unroll
      for (int j = 0; j < 8; ++j)
        bq.u[j] = *(const unsigned short*)(qb + (size_t)(g * 8 + j) * 8192 + n0 + l15);
      f32x4 st[4];
#pragma unroll
      for (int tile = 0; tile < 4; ++tile) {
        f32x4 z = {};
        st[tile] = MFMA(ka[tile], bq.v, z);
      }
      float m = st[0][0];
#pragma unroll
      for (int tile = 0; tile < 4; ++tile)
#pragma unroll
        for (int rr = 0; rr < 4; ++rr) m = fmaxf(m, st[tile][rr]);
      m = fmaxf(m, __shfl_xor(m, 16, 64));
      m = fmaxf(m, __shfl_xor(m, 32, 64));
      float sum = 0.f;
#pragma unroll
      for (int tile = 0; tile < 4; ++tile) {
        bf16x4 p4;
#pragma unroll
        for (int rr = 0; rr < 4; ++rr) {
          const float ex = __expf(st[tile][rr] - m);
          sum += ex;
          p4[rr] = (__bf16)ex;
        }
        *(bf16x4*)(Pw + l15 * 72 + tile * 16 + g * 4) = p4;
      }
      sum += __shfl_xor(sum, 16, 64);
      sum += __shfl_xor(sum, 32, 64);
      const float inv = 1.0f / sum;
      f32x4 o[2] = {};
#pragma unroll
      for (int kh = 0; kh < 2; ++kh) {
        const bf16x8 pf = *(const bf16x8*)(Pw + l15 * 72 + kh * 32 + g * 8);
#pragma unroll
        for (int mi = 0; mi < 2; ++mi) o[mi] = MFMA(va[mi][kh], pf, o[mi]);
      }
#pragma unroll
      for (int mi = 0; mi < 2; ++mi)
#pragma unroll
        for (int rr = 0; rr < 4; ++rr) {
          const int d = mi * 16 + g * 4 + rr;
          xsa[(size_t)(bh * 32 + d) * 8192 + n0 + l15] = (__bf16)(o[mi][rr] * inv);
        }
    }
  }
}

// ---------------- K6: output projections (both halves) -----------------------
__global__ __launch_bounds__(256) void k_out(const __bf16* __restrict__ xsa,
                                             const __bf16* __restrict__ xca,
                                             const __bf16* __restrict__ Wo1,
                                             const __bf16* __restrict__ bo1,
                                             const __bf16* __restrict__ Wo2,
                                             const __bf16* __restrict__ bo2,
                                             void* __restrict__ outv,
                                             const void* __restrict__ xsrc) {
  __shared__ alignas(16) __bf16 As[128 * 32];
  __shared__ alignas(16) __bf16 Bs[128 * 32];
  const int t = threadIdx.x, lane = t & 63;
  const int wr = t >> 7, wc = (t >> 6) & 1;
  const int l15 = lane & 15, g = lane >> 4;
  const int nt = blockIdx.x, b = blockIdx.y, br = blockIdx.z;
  const int isf32 = detect_f32((const unsigned int*)xsrc);
  const __bf16* Wo = br ? Wo2 : Wo1;
  const __bf16* bo = br ? bo2 : bo1;
  f32x4 acc[4][4] = {};
  const int r = t >> 2;
  const int c8 = ((t & 3) ^ ((t >> 3) & 3)) * 8;
  const int cx = ((g ^ ((l15 >> 1) & 3)) * 8);
  for (int k0 = 0; k0 < 256; k0 += 32) {
#pragma unroll
    for (int i = 0; i < 2; ++i) {
      const int row = nt * 128 + i * 64 + r;
      const __bf16* ga;
      if (br == 0) {
        // x_sa_mat[b,row,c] = xsa[b][(row>>5)&7][row>>8][(row&31)*256 + c]
        ga = xsa + (size_t)((b * 8 + ((row >> 5) & 7)) * 32 + (row >> 8)) * 8192 +
             (row & 31) * 256 + k0 + c8;
      } else {
        ga = xca + (size_t)(b * 8192 + row) * 256 + k0 + c8;
      }
      gl2lds16(ga, As + i * 2048 + t * 8);
      gl2lds16(Wo + (size_t)(i * 64 + r) * 256 + k0 + c8, Bs + i * 2048 + t * 8);
    }
    __syncthreads();
    bf16x8 af[4], bfr[4];
#pragma unroll
    for (int i = 0; i < 4; ++i) {
      af[i] = *(const bf16x8*)(As + (wr * 64 + i * 16 + l15) * 32 + cx);
      bfr[i] = *(const bf16x8*)(Bs + (wc * 64 + i * 16 + l15) * 32 + cx);
    }
#pragma unroll
    for (int i = 0; i < 4; ++i)
#pragma unroll
      for (int j = 0; j < 4; ++j) acc[i][j] = MFMA(af[i], bfr[j], acc[i][j]);
    __syncthreads();
  }
  float bias[4];
#pragma unroll
  for (int j = 0; j < 4; ++j) bias[j] = (float)bo[wc * 64 + j * 16 + l15];
#pragma unroll
  for (int i = 0; i < 4; ++i) {
#pragma unroll
    for (int j = 0; j < 4; ++j) {
      const int col = wc * 64 + j * 16 + l15;
#pragma unroll
      for (int rr = 0; rr < 4; ++rr) {
        const int row = nt * 128 + wr * 64 + i * 16 + g * 4 + rr;
        const float val = acc[i][j][rr] + bias[j];
        const size_t oi = (size_t)(b * 8192 + row) * 256 + br * 128 + col;
        if (isf32) ((float*)outv)[oi] = val;
        else ((__bf16*)outv)[oi] = (__bf16)val;
      }
    }
  }
}

extern "C" void kernel_launch(void* const* d_in, const int* in_sizes, int n_in,
                              void* d_out, int out_size, void* d_ws, size_t ws_size,
                              hipStream_t stream) {
  char* ws = (char*)d_ws;
  __bf16* qkvv   = (__bf16*)(ws);                    // 134,217,728 B
  __bf16* xca    = (__bf16*)(ws + 134217728ull);     //  32 MB (region A)
  float*  pbuf   = (float*)(ws + 167772160ull);      //  16 MB (region B)
  float*  npart  = (float*)(ws + 184549376ull);      //   2 MB (region C; dead after k_nred)
  float*  spart  = (float*)(ws + 184549376ull);      //   8 MB (alias C, written later)
  __bf16* xsa    = (__bf16*)(ws + 167772160ull);     //  alias B (pbuf/spart dead by then)
  __bf16* kprojT = (__bf16*)(ws + 201326592ull);     //  262,144 B
  __bf16* vprojb = (__bf16*)(ws + 201588736ull);     //  262,144 B
  float*  qsum   = (float*)(ws + 201850880ull);      //    8,192 B
  float*  ksum   = (float*)(ws + 201859072ull);      //    8,192 B
  __bf16* attnb  = (__bf16*)(ws + 201867264ull);     //  131,072 B
  __bf16* cw     = (__bf16*)(ws + 201998336ull);     //  2,753,536 B

  __bf16* cWq  = cw;
  __bf16* cWE  = cw + 262144;
  __bf16* cbE  = cw + 786432;
  __bf16* cWF  = cw + 786496;
  __bf16* cbF  = cw + 1310784;
  __bf16* cWo1 = cw + 1310848;
  __bf16* cbo1 = cw + 1343616;
  __bf16* cWo2 = cw + 1343744;
  __bf16* cbo2 = cw + 1376512;
  __bf16* ct1  = cw + 1376640;
  __bf16* ct2  = cw + 1376648;

  k_convert_w<<<673, 256, 0, stream>>>(d_in[1], d_in[2], d_in[3], d_in[4], d_in[5],
                                       d_in[6], d_in[7], d_in[8], d_in[9], d_in[10],
                                       d_in[11], cw, d_in[0]);
  k_qkvv<<<dim3(1024), 256, 0, stream>>>(d_in[0], cWq, qkvv, npart);
  k_nred<<<16, 256, 0, stream>>>(npart, qsum, ksum);
  k_proj_part<<<dim3(16, 16, 2), 256, 0, stream>>>(qkvv, cWE, cWF, pbuf);
  k_proj_reduce<<<dim3(1024), 256, 0, stream>>>(pbuf, cbE, cbF, qsum, ct2, kprojT, vprojb);
  k_sca_part<<<dim3(64, 8), 256, 0, stream>>>(qkvv, spart);
  k_sca_softmax<<<dim3(64), 256, 0, stream>>>(spart, qsum, ksum, ct1, attnb);
  k_casa<<<dim3(32, 128), 256, 0, stream>>>(qkvv, attnb, kprojT, vprojb, xca, xsa);
  k_out<<<dim3(64, 8, 2), 256, 0, stream>>>(xsa, xca, cWo1, cbo1, cWo2, cbo2, d_out, d_in[0]);
}

// Round 2
// 335.603 us; speedup vs baseline: 1.0156x; 1.0156x over previous
//
#include <hip/hip_runtime.h>
#include <hip/hip_bf16.h>
#include <stdint.h>

// Problem: B=8, N=8192, C=256, H=8, D=32, P=64, F=4C=1024
// qkvv layout: [part(4)][b(8)][h*32+d(256)][n(8192)] bf16, n contiguous.
// Inputs self-detected as fp32-or-bf16. x is converted to bf16 INSIDE k_qkvv's
// B-staging path (reg-stage + ds_write; no separate convert kernel); weights
// canonicalized by k_convert_w. k_qkvv v3 = v1 tile structure (128x128, LDS
// staged, proven swizzle + transpose epilogue) + 2-phase double-buffered
// K-loop (stage k+1 overlapped with MFMA of k) + grid (f,tok) so same-x
// blocks dispatch together (L2/L3-hot x re-reads).

typedef __attribute__((ext_vector_type(8))) __bf16 bf16x8;
typedef __attribute__((ext_vector_type(4))) __bf16 bf16x4;
typedef __attribute__((ext_vector_type(4))) float f32x4;

#define MFMA(a, b, c) __builtin_amdgcn_mfma_f32_16x16x32_bf16((a), (b), (c), 0, 0, 0)

__device__ __forceinline__ void gl2lds16(const __bf16* g, __bf16* l) {
  __builtin_amdgcn_global_load_lds(
      (const __attribute__((address_space(1))) void*)(const void*)g,
      (__attribute__((address_space(3))) void*)(void*)l, 16, 0, 0);
}

// Self-detect: sample x's first 64 dwords (uniform scalar loads). fp32 data's
// low halfwords are mantissa bytes -> exponent field >= 0xC0 w.p. ~1/4; real
// bf16 N(0,1)-scale data never has exp >= 0xC0.
__device__ __forceinline__ int detect_f32(const unsigned int* __restrict__ xw) {
  int c = 0;
#pragma unroll
  for (int i = 0; i < 64; ++i) {
    const unsigned int u = xw[i];
    c += (((u >> 7) & 0xFF) >= 0xC0) ? 1 : 0;
    c += (((u >> 23) & 0xFF) >= 0xC0) ? 1 : 0;
  }
  return c > 8;
}

// ---------------- K0b: canonicalize the 11 weight/bias/temp inputs -----------
__global__ __launch_bounds__(256) void k_convert_w(
    const void* s0, const void* s1, const void* s2, const void* s3, const void* s4,
    const void* s5, const void* s6, const void* s7, const void* s8, const void* s9,
    const void* s10, __bf16* __restrict__ cw, const void* __restrict__ xsrc) {
  const int i = (blockIdx.x * 256 + threadIdx.x) * 8;
  if (i >= 1376656) return;
  const void* s;
  int base;
  if (i < 262144)        { s = s0;  base = 0; }
  else if (i < 786432)   { s = s1;  base = 262144; }
  else if (i < 786496)   { s = s2;  base = 786432; }
  else if (i < 1310784)  { s = s3;  base = 786496; }
  else if (i < 1310848)  { s = s4;  base = 1310784; }
  else if (i < 1343616)  { s = s5;  base = 1310848; }
  else if (i < 1343744)  { s = s6;  base = 1343616; }
  else if (i < 1376512)  { s = s7;  base = 1343744; }
  else if (i < 1376640)  { s = s8;  base = 1376512; }
  else if (i < 1376648)  { s = s9;  base = 1376640; }
  else                   { s = s10; base = 1376648; }
  const int li = i - base;
  if (detect_f32((const unsigned int*)xsrc)) {
    const float* sf = (const float*)s;
#pragma unroll
    for (int j = 0; j < 8; ++j) cw[i + j] = (__bf16)sf[li + j];
  } else {
    const __bf16* sb = (const __bf16*)s;
#pragma unroll
    for (int j = 0; j < 8; ++j) cw[i + j] = sb[li + j];
  }
}

// ---------------- K1: qkvv = x @ Wqkvv^T (v3: 2-phase pipeline, fused cvt) ---
__global__ __launch_bounds__(256) void k_qkvv(const void* __restrict__ xsrc,
                                              const __bf16* __restrict__ Wq,
                                              __bf16* __restrict__ qkvv,
                                              float* __restrict__ npart) {
  __shared__ alignas(16) __bf16 As[2][128 * 32];
  __shared__ alignas(16) __bf16 Bs[2][128 * 32];
  __shared__ alignas(16) __bf16 Cs[32 * 136];  // transpose tile, padded stride
  const int t = threadIdx.x, lane = t & 63;
  const int wr = t >> 7, wc = (t >> 6) & 1;
  const int l15 = lane & 15, g = lane >> 4;
  const int f0 = blockIdx.x * 128;   // f-tile (8)
  const int t0 = blockIdx.y * 128;   // token-tile (512); same-x blocks adjacent
  const int isf32 = detect_f32((const unsigned int*)xsrc);
  const float* xf = (const float*)xsrc;
  const __bf16* xb = (const __bf16*)xsrc;
  f32x4 acc[4][4] = {};
  const int r = t >> 2;
  const int c8 = ((t & 3) ^ ((t >> 3) & 3)) * 8;  // staged (swizzled) chunk
  const int cx = ((g ^ ((l15 >> 1) & 3)) * 8);    // read-side chunk

  // ---- prologue: stage k-step 0 into buffer 0
  if (isf32) {
#pragma unroll
    for (int i = 0; i < 2; ++i) {
      gl2lds16(Wq + (size_t)(f0 + i * 64 + r) * 256 + c8, &As[0][i * 2048 + t * 8]);
      const float* src = xf + (size_t)(t0 + i * 64 + r) * 256 + c8;
      const f32x4 a = *(const f32x4*)src;
      const f32x4 a2 = *(const f32x4*)(src + 4);
      bf16x8 v;
#pragma unroll
      for (int j = 0; j < 4; ++j) { v[j] = (__bf16)a[j]; v[4 + j] = (__bf16)a2[j]; }
      *(bf16x8*)(&Bs[0][i * 2048 + t * 8]) = v;
    }
  } else {
#pragma unroll
    for (int i = 0; i < 2; ++i) {
      gl2lds16(Wq + (size_t)(f0 + i * 64 + r) * 256 + c8, &As[0][i * 2048 + t * 8]);
      gl2lds16(xb + (size_t)(t0 + i * 64 + r) * 256 + c8, &Bs[0][i * 2048 + t * 8]);
    }
  }
  __syncthreads();

  // ---- 2-phase K loop: stage k+1 (issue early), MFMA k, write-late, barrier
  for (int ks = 0; ks < 8; ++ks) {
    const int cur = ks & 1, nxt = cur ^ 1;
    const int k1 = (ks + 1) * 32;
    f32x4 a[2], a2[2];
    if (ks < 7) {
#pragma unroll
      for (int i = 0; i < 2; ++i)
        gl2lds16(Wq + (size_t)(f0 + i * 64 + r) * 256 + k1 + c8, &As[nxt][i * 2048 + t * 8]);
      if (isf32) {
#pragma unroll
        for (int i = 0; i < 2; ++i) {
          const float* src = xf + (size_t)(t0 + i * 64 + r) * 256 + k1 + c8;
          a[i] = *(const f32x4*)src;
          a2[i] = *(const f32x4*)(src + 4);
        }
      } else {
#pragma unroll
        for (int i = 0; i < 2; ++i)
          gl2lds16(xb + (size_t)(t0 + i * 64 + r) * 256 + k1 + c8, &Bs[nxt][i * 2048 + t * 8]);
      }
    }
    bf16x8 af[4], bfr[4];
#pragma unroll
    for (int i = 0; i < 4; ++i) {
      af[i] = *(const bf16x8*)(&As[cur][(wr * 64 + i * 16 + l15) * 32 + cx]);
      bfr[i] = *(const bf16x8*)(&Bs[cur][(wc * 64 + i * 16 + l15) * 32 + cx]);
    }
#pragma unroll
    for (int i = 0; i < 4; ++i)
#pragma unroll
      for (int j = 0; j < 4; ++j) acc[i][j] = MFMA(af[i], bfr[j], acc[i][j]);
    if (ks < 7 && isf32) {  // write-late: HBM latency hidden under the MFMAs
#pragma unroll
      for (int i = 0; i < 2; ++i) {
        bf16x8 v;
#pragma unroll
        for (int j = 0; j < 4; ++j) { v[j] = (__bf16)a[i][j]; v[4 + j] = (__bf16)a2[i][j]; }
        *(bf16x8*)(&Bs[nxt][i * 2048 + t * 8]) = v;
      }
    }
    __syncthreads();
  }

  const int b = t0 >> 13;
  const int n0 = t0 & 8191;
  // Epilogue: per 32-f slab, stage to LDS, emit 256B-dense row stores + norm partials.
  for (int i = 0; i < 4; ++i) {
    if (i) __syncthreads();  // protect Cs from previous iteration's readers
#pragma unroll
    for (int j = 0; j < 4; ++j)
#pragma unroll
      for (int rr = 0; rr < 4; ++rr)
        Cs[(wr * 16 + g * 4 + rr) * 136 + wc * 64 + j * 16 + l15] = (__bf16)acc[i][j][rr];
    __syncthreads();
#pragma unroll
    for (int half = 0; half < 2; ++half) {
      const int row_l = (t >> 4) + half * 16;     // [0,32): 16 threads per row
      const int col8 = (t & 15) * 8;              // [0,128) in steps of 8
      const bf16x8 v = *(const bf16x8*)(Cs + row_l * 136 + col8);
      const int f = f0 + (row_l >> 4) * 64 + i * 16 + (row_l & 15);
      *(bf16x8*)(qkvv + (size_t)(((f >> 8) * 8 + b) * 256 + (f & 255)) * 8192 + n0 + col8) = v;
      if (f0 < 512) {  // q (f<256) and k (256<=f<512) L2-norm partial sums
        float s = 0.f;
#pragma unroll
        for (int jj = 0; jj < 8; ++jj) { const float q = (float)v[jj]; s += q * q; }
#pragma unroll
        for (int off = 1; off < 16; off <<= 1) s += __shfl_xor(s, off, 16);
        if ((t & 15) == 0) npart[(size_t)blockIdx.y * 512 + f] = s;
      }
    }
  }
}

// ---------------- K1b: reduce norm partials over the 64 token-blocks of each b
__global__ __launch_bounds__(256) void k_nred(const float* __restrict__ npart,
                                              float* __restrict__ qsum,
                                              float* __restrict__ ksum) {
  const int which = blockIdx.x >> 3, b = blockIdx.x & 7;
  const int c = threadIdx.x;
  float s = 0.f;
#pragma unroll 4
  for (int j = 0; j < 64; ++j)
    s += npart[(size_t)(b * 64 + j) * 512 + which * 256 + c];
  (which ? ksum : qsum)[b * 256 + c] = s;
}

// ---------------- K3: k_proj / v_proj partial GEMMs (K-split) ----------------
__global__ __launch_bounds__(256) void k_proj_part(const __bf16* __restrict__ qkvv,
                                                   const __bf16* __restrict__ WE,
                                                   const __bf16* __restrict__ WF,
                                                   float* __restrict__ pbuf) {
  __shared__ alignas(16) __bf16 As[128 * 32];
  __shared__ alignas(16) __bf16 Bs[64 * 32];
  const int t = threadIdx.x, lane = t & 63;
  const int wr = t >> 7, wc = (t >> 6) & 1;
  const int l15 = lane & 15, g = lane >> 4;
  const int kc = blockIdx.x, mt = blockIdx.y, pj = blockIdx.z;
  const __bf16* A = qkvv + (size_t)(pj ? 3 : 1) * 2048 * 8192;
  const __bf16* Bm = pj ? WF : WE;
  const int r0 = mt * 128;
  f32x4 acc[4][2] = {};
  const int r = t >> 2;
  const int c8 = ((t & 3) ^ ((t >> 3) & 3)) * 8;
  const int cx = ((g ^ ((l15 >> 1) & 3)) * 8);
  for (int k0 = kc * 512; k0 < kc * 512 + 512; k0 += 32) {
#pragma unroll
    for (int i = 0; i < 2; ++i)
      gl2lds16(A + (size_t)(r0 + i * 64 + r) * 8192 + k0 + c8, As + i * 2048 + t * 8);
    gl2lds16(Bm + (size_t)r * 8192 + k0 + c8, Bs + t * 8);
    __syncthreads();
    bf16x8 af[4], bfr[2];
#pragma unroll
    for (int i = 0; i < 4; ++i)
      af[i] = *(const bf16x8*)(As + (wr * 64 + i * 16 + l15) * 32 + cx);
#pragma unroll
    for (int j = 0; j < 2; ++j)
      bfr[j] = *(const bf16x8*)(Bs + (wc * 32 + j * 16 + l15) * 32 + cx);
#pragma unroll
    for (int i = 0; i < 4; ++i)
#pragma unroll
      for (int j = 0; j < 2; ++j) acc[i][j] = MFMA(af[i], bfr[j], acc[i][j]);
    __syncthreads();
  }
  float* dst = pbuf + (size_t)((pj * 16 + kc) * 2048 + r0) * 64;
#pragma unroll
  for (int i = 0; i < 4; ++i)
#pragma unroll
    for (int j = 0; j < 2; ++j)
#pragma unroll
      for (int rr = 0; rr < 4; ++rr)
        dst[(wr * 64 + i * 16 + g * 4 + rr) * 64 + wc * 32 + j * 16 + l15] = acc[i][j][rr];
}

// ---------------- K3b: reduce + bias; emit bf16 MFMA-operand copies ----------
__global__ __launch_bounds__(256) void k_proj_reduce(const float* __restrict__ pbuf,
                                                     const __bf16* __restrict__ bE,
                                                     const __bf16* __restrict__ bF,
                                                     const float* __restrict__ qsum,
                                                     const __bf16* __restrict__ t2,
                                                     __bf16* __restrict__ kprojT,
                                                     __bf16* __restrict__ vprojb) {
  const int idx = blockIdx.x * 256 + threadIdx.x;  // [0, 262144)
  const int pj = idx >> 17, rp = idx & 131071, p = idx & 63;
  const int row = rp >> 6, bh = row >> 5, d = row & 31, h = bh & 7;
  float s = (float)((pj ? bF : bE)[p]);
  const float* src = pbuf + (size_t)pj * 16 * 131072 + rp;
#pragma unroll
  for (int k = 0; k < 16; ++k) s += src[(size_t)k * 131072];
  if (pj == 0) {
    const float qi = 1.0f / fmaxf(sqrtf(qsum[row]), 1e-12f);
    kprojT[bh * 2048 + p * 32 + d] = (__bf16)(s * qi * (float)t2[h]);
  } else {
    vprojb[bh * 2048 + d * 64 + p] = (__bf16)s;
  }
}

// ---------------- K4a: S[d,e] = q . k partials (K-split 8 x 4 waves) ---------
__global__ __launch_bounds__(256) void k_sca_part(const __bf16* __restrict__ qkvv,
                                                  float* __restrict__ spart) {
  const int bh = blockIdx.x, kc = blockIdx.y;
  const int t = threadIdx.x, lane = t & 63, w = t >> 6;
  const __bf16* qb = qkvv + (size_t)(bh * 32) * 8192;
  const __bf16* kb = qkvv + (size_t)(2048 + bh * 32) * 8192;
  f32x4 acc[2][2] = {};
  const int kbase = kc * 1024 + w * 256 + (lane >> 4) * 8;
#pragma unroll
  for (int ks = 0; ks < 256; ks += 32) {
    bf16x8 af[2], bfr[2];
#pragma unroll
    for (int i = 0; i < 2; ++i) {
      af[i] = *(const bf16x8*)(qb + (size_t)(i * 16 + (lane & 15)) * 8192 + kbase + ks);
      bfr[i] = *(const bf16x8*)(kb + (size_t)(i * 16 + (lane & 15)) * 8192 + kbase + ks);
    }
#pragma unroll
    for (int i = 0; i < 2; ++i)
#pragma unroll
      for (int j = 0; j < 2; ++j) acc[i][j] = MFMA(af[i], bfr[j], acc[i][j]);
  }
  float* dst = spart + (size_t)((bh * 8 + kc) * 4 + w) * 1024;
#pragma unroll
  for (int i = 0; i < 2; ++i)
#pragma unroll
    for (int j = 0; j < 2; ++j)
#pragma unroll
      for (int rr = 0; rr < 4; ++rr)
        dst[(i * 16 + (lane >> 4) * 4 + rr) * 32 + j * 16 + (lane & 15)] = acc[i][j][rr];
}

// ---------------- K4b: reduce, scale, softmax over e; emit bf16 attn [d][e] --
__global__ __launch_bounds__(256) void k_sca_softmax(const float* __restrict__ spart,
                                                     const float* __restrict__ qsum,
                                                     const float* __restrict__ ksum,
                                                     const __bf16* __restrict__ temp1,
                                                     __bf16* __restrict__ attnb) {
  const int bh = blockIdx.x;
  __shared__ float S[1024];
  const int t = threadIdx.x;
  const float tmp = (float)temp1[bh & 7];
  for (int idx = t; idx < 1024; idx += 256) {
    float s = 0.f;
    const float* src = spart + (size_t)bh * 32768 + idx;
#pragma unroll
    for (int k = 0; k < 32; ++k) s += src[k * 1024];
    const float qi = 1.0f / fmaxf(sqrtf(qsum[bh * 32 + (idx >> 5)]), 1e-12f);
    const float ki = 1.0f / fmaxf(sqrtf(ksum[bh * 32 + (idx & 31)]), 1e-12f);
    S[idx] = s * qi * ki * tmp;
  }
  __syncthreads();
  const int lane = t & 63, w = t >> 6;
#pragma unroll
  for (int rr = 0; rr < 4; ++rr) {
    const int row = rr * 8 + w * 2 + (lane >> 5);
    const int e = lane & 31;
    float v = S[row * 32 + e];
    float m = v;
#pragma unroll
    for (int off = 16; off; off >>= 1) m = fmaxf(m, __shfl_xor(m, off, 32));
    const float ex = __expf(v - m);
    float sm = ex;
#pragma unroll
    for (int off = 16; off; off >>= 1) sm += __shfl_xor(sm, off, 32);
    attnb[(size_t)bh * 1024 + row * 32 + e] = (__bf16)(ex / sm);
  }
}

// ---------------- K4c/K5 merged: channel-attn apply + spatial attention ------
__global__ __launch_bounds__(256) void k_casa(const __bf16* __restrict__ qkvv,
                                              const __bf16* __restrict__ attnb,
                                              const __bf16* __restrict__ kprojT,
                                              const __bf16* __restrict__ vprojb,
                                              __bf16* __restrict__ xca,
                                              __bf16* __restrict__ xsa) {
  __shared__ __bf16 P[4][16 * 72];  // used by the sa branch only
  const int t = threadIdx.x, lane = t & 63, w = t >> 6;
  const int l15 = lane & 15, g = lane >> 4;
  if (blockIdx.y < 64) {
    // ---- channel attention: x_ca[d][tok] = sum_e attn[d][e] * v_ca[e][tok]
    const int bh = blockIdx.y, b = bh >> 3, h = bh & 7;
    const __bf16* vb = qkvv + (size_t)(4096 + bh * 32) * 8192;
    bf16x8 aa[2];
#pragma unroll
    for (int mi = 0; mi < 2; ++mi)
      aa[mi] = *(const bf16x8*)(attnb + bh * 1024 + (mi * 16 + l15) * 32 + g * 8);
#pragma unroll
    for (int it = 0; it < 4; ++it) {
      const int n = blockIdx.x * 256 + it * 64 + w * 16 + l15;
      union { bf16x8 v; unsigned short u[8]; } bq;
#pragma unroll
      for (int j = 0; j < 8; ++j)
        bq.u[j] = *(const unsigned short*)(vb + (size_t)(g * 8 + j) * 8192 + n);
      f32x4 o[2] = {};
#pragma unroll
      for (int mi = 0; mi < 2; ++mi) o[mi] = MFMA(aa[mi], bq.v, o[mi]);
#pragma unroll
      for (int mi = 0; mi < 2; ++mi) {
        bf16x4 p4;
#pragma unroll
        for (int rr = 0; rr < 4; ++rr) p4[rr] = (__bf16)o[mi][rr];
        *(bf16x4*)(xca + (size_t)(b * 8192 + n) * 256 + h * 32 + mi * 16 + g * 4) = p4;
      }
    }
  } else {
    // ---- spatial (low-rank) attention
    const int bh = blockIdx.y - 64;
    const __bf16* qb = qkvv + (size_t)(bh * 32) * 8192;
    bf16x8 ka[4], va[2][2];
#pragma unroll
    for (int tile = 0; tile < 4; ++tile)
      ka[tile] = *(const bf16x8*)(kprojT + bh * 2048 + (tile * 16 + l15) * 32 + g * 8);
#pragma unroll
    for (int mi = 0; mi < 2; ++mi)
#pragma unroll
      for (int kh = 0; kh < 2; ++kh)
        va[mi][kh] = *(const bf16x8*)(vprojb + bh * 2048 + (mi * 16 + l15) * 64 + kh * 32 + g * 8);
    __bf16* Pw = &P[w][0];
#pragma unroll
    for (int it = 0; it < 4; ++it) {
      const int n0 = blockIdx.x * 256 + it * 64 + w * 16;
      union { bf16x8 v; unsigned short u[8]; } bq;
#pragma unroll
      for (int j = 0; j < 8; ++j)
        bq.u[j] = *(const unsigned short*)(qb + (size_t)(g * 8 + j) * 8192 + n0 + l15);
      f32x4 st[4];
#pragma unroll
      for (int tile = 0; tile < 4; ++tile) {
        f32x4 z = {};
        st[tile] = MFMA(ka[tile], bq.v, z);
      }
      float m = st[0][0];
#pragma unroll
      for (int tile = 0; tile < 4; ++tile)
#pragma unroll
        for (int rr = 0; rr < 4; ++rr) m = fmaxf(m, st[tile][rr]);
      m = fmaxf(m, __shfl_xor(m, 16, 64));
      m = fmaxf(m, __shfl_xor(m, 32, 64));
      float sum = 0.f;
#pragma unroll
      for (int tile = 0; tile < 4; ++tile) {
        bf16x4 p4;
#pragma unroll
        for (int rr = 0; rr < 4; ++rr) {
          const float ex = __expf(st[tile][rr] - m);
          sum += ex;
          p4[rr] = (__bf16)ex;
        }
        *(bf16x4*)(Pw + l15 * 72 + tile * 16 + g * 4) = p4;
      }
      sum += __shfl_xor(sum, 16, 64);
      sum += __shfl_xor(sum, 32, 64);
      const float inv = 1.0f / sum;
      f32x4 o[2] = {};
#pragma unroll
      for (int kh = 0; kh < 2; ++kh) {
        const bf16x8 pf = *(const bf16x8*)(Pw + l15 * 72 + kh * 32 + g * 8);
#pragma unroll
        for (int mi = 0; mi < 2; ++mi) o[mi] = MFMA(va[mi][kh], pf, o[mi]);
      }
#pragma unroll
      for (int mi = 0; mi < 2; ++mi)
#pragma unroll
        for (int rr = 0; rr < 4; ++rr) {
          const int d = mi * 16 + g * 4 + rr;
          xsa[(size_t)(bh * 32 + d) * 8192 + n0 + l15] = (__bf16)(o[mi][rr] * inv);
        }
    }
  }
}

// ---------------- K6: output projections (both halves) -----------------------
__global__ __launch_bounds__(256) void k_out(const __bf16* __restrict__ xsa,
                                             const __bf16* __restrict__ xca,
                                             const __bf16* __restrict__ Wo1,
                                             const __bf16* __restrict__ bo1,
                                             const __bf16* __restrict__ Wo2,
                                             const __bf16* __restrict__ bo2,
                                             void* __restrict__ outv,
                                             const void* __restrict__ xsrc) {
  __shared__ alignas(16) __bf16 As[128 * 32];
  __shared__ alignas(16) __bf16 Bs[128 * 32];
  const int t = threadIdx.x, lane = t & 63;
  const int wr = t >> 7, wc = (t >> 6) & 1;
  const int l15 = lane & 15, g = lane >> 4;
  const int nt = blockIdx.x, b = blockIdx.y, br = blockIdx.z;
  const int isf32 = detect_f32((const unsigned int*)xsrc);
  const __bf16* Wo = br ? Wo2 : Wo1;
  const __bf16* bo = br ? bo2 : bo1;
  f32x4 acc[4][4] = {};
  const int r = t >> 2;
  const int c8 = ((t & 3) ^ ((t >> 3) & 3)) * 8;
  const int cx = ((g ^ ((l15 >> 1) & 3)) * 8);
  for (int k0 = 0; k0 < 256; k0 += 32) {
#pragma unroll
    for (int i = 0; i < 2; ++i) {
      const int row = nt * 128 + i * 64 + r;
      const __bf16* ga;
      if (br == 0) {
        // x_sa_mat[b,row,c] = xsa[b][(row>>5)&7][row>>8][(row&31)*256 + c]
        ga = xsa + (size_t)((b * 8 + ((row >> 5) & 7)) * 32 + (row >> 8)) * 8192 +
             (row & 31) * 256 + k0 + c8;
      } else {
        ga = xca + (size_t)(b * 8192 + row) * 256 + k0 + c8;
      }
      gl2lds16(ga, As + i * 2048 + t * 8);
      gl2lds16(Wo + (size_t)(i * 64 + r) * 256 + k0 + c8, Bs + i * 2048 + t * 8);
    }
    __syncthreads();
    bf16x8 af[4], bfr[4];
#pragma unroll
    for (int i = 0; i < 4; ++i) {
      af[i] = *(const bf16x8*)(As + (wr * 64 + i * 16 + l15) * 32 + cx);
      bfr[i] = *(const bf16x8*)(Bs + (wc * 64 + i * 16 + l15) * 32 + cx);
    }
#pragma unroll
    for (int i = 0; i < 4; ++i)
#pragma unroll
      for (int j = 0; j < 4; ++j) acc[i][j] = MFMA(af[i], bfr[j], acc[i][j]);
    __syncthreads();
  }
  float bias[4];
#pragma unroll
  for (int j = 0; j < 4; ++j) bias[j] = (float)bo[wc * 64 + j * 16 + l15];
#pragma unroll
  for (int i = 0; i < 4; ++i) {
#pragma unroll
    for (int j = 0; j < 4; ++j) {
      const int col = wc * 64 + j * 16 + l15;
#pragma unroll
      for (int rr = 0; rr < 4; ++rr) {
        const int row = nt * 128 + wr * 64 + i * 16 + g * 4 + rr;
        const float val = acc[i][j][rr] + bias[j];
        const size_t oi = (size_t)(b * 8192 + row) * 256 + br * 128 + col;
        if (isf32) ((float*)outv)[oi] = val;
        else ((__bf16*)outv)[oi] = (__bf16)val;
      }
    }
  }
}

extern "C" void kernel_launch(void* const* d_in, const int* in_sizes, int n_in,
                              void* d_out, int out_size, void* d_ws, size_t ws_size,
                              hipStream_t stream) {
  char* ws = (char*)d_ws;
  __bf16* qkvv   = (__bf16*)(ws);                    // 134,217,728 B
  __bf16* xca    = (__bf16*)(ws + 134217728ull);     //  32 MB (region A)
  float*  pbuf   = (float*)(ws + 167772160ull);      //  16 MB (region B)
  float*  npart  = (float*)(ws + 184549376ull);      //   1 MB (region C; dead after k_nred)
  float*  spart  = (float*)(ws + 184549376ull);      //   8 MB (alias C, written later)
  __bf16* xsa    = (__bf16*)(ws + 167772160ull);     //  alias B (pbuf/spart dead by then)
  __bf16* kprojT = (__bf16*)(ws + 201326592ull);     //  262,144 B
  __bf16* vprojb = (__bf16*)(ws + 201588736ull);     //  262,144 B
  float*  qsum   = (float*)(ws + 201850880ull);      //    8,192 B
  float*  ksum   = (float*)(ws + 201859072ull);      //    8,192 B
  __bf16* attnb  = (__bf16*)(ws + 201867264ull);     //  131,072 B
  __bf16* cw     = (__bf16*)(ws + 201998336ull);     //  2,753,536 B

  __bf16* cWq  = cw;
  __bf16* cWE  = cw + 262144;
  __bf16* cbE  = cw + 786432;
  __bf16* cWF  = cw + 786496;
  __bf16* cbF  = cw + 1310784;
  __bf16* cWo1 = cw + 1310848;
  __bf16* cbo1 = cw + 1343616;
  __bf16* cWo2 = cw + 1343744;
  __bf16* cbo2 = cw + 1376512;
  __bf16* ct1  = cw + 1376640;
  __bf16* ct2  = cw + 1376648;

  k_convert_w<<<673, 256, 0, stream>>>(d_in[1], d_in[2], d_in[3], d_in[4], d_in[5],
                                       d_in[6], d_in[7], d_in[8], d_in[9], d_in[10],
                                       d_in[11], cw, d_in[0]);
  k_qkvv<<<dim3(8, 512), 256, 0, stream>>>(d_in[0], cWq, qkvv, npart);
  k_nred<<<16, 256, 0, stream>>>(npart, qsum, ksum);
  k_proj_part<<<dim3(16, 16, 2), 256, 0, stream>>>(qkvv, cWE, cWF, pbuf);
  k_proj_reduce<<<dim3(1024), 256, 0, stream>>>(pbuf, cbE, cbF, qsum, ct2, kprojT, vprojb);
  k_sca_part<<<dim3(64, 8), 256, 0, stream>>>(qkvv, spart);
  k_sca_softmax<<<dim3(64), 256, 0, stream>>>(spart, qsum, ksum, ct1, attnb);
  k_casa<<<dim3(32, 128), 256, 0, stream>>>(qkvv, attnb, kprojT, vprojb, xca, xsa);
  k_out<<<dim3(64, 8, 2), 256, 0, stream>>>(xsa, xca, cWo1, cbo1, cWo2, cbo2, d_out, d_in[0]);
}

// Round 3
// 314.048 us; speedup vs baseline: 1.0853x; 1.0686x over previous
//
#include <hip/hip_runtime.h>
#include <hip/hip_bf16.h>
#include <stdint.h>

// Problem: B=8, N=8192, C=256, H=8, D=32, P=64, F=4C=1024
// qkvv layout: [part(4)][b(8)][h*32+d(256)][n(8192)] bf16, n contiguous.
// Inputs self-detected as fp32-or-bf16; x canonicalized to bf16 by k_convert_x
// (measured near its BW floor; fusing it into k_qkvv regressed twice: v2
// latency-bound, v3 fp32 re-fetch 264MB). All three LDS-staged GEMMs use a
// 2-phase double-buffered K-loop: stage(k+1) issued before MFMA(k), ONE
// barrier per step. Proven v1 swizzles/epilogues/grids kept verbatim.

typedef __attribute__((ext_vector_type(8))) __bf16 bf16x8;
typedef __attribute__((ext_vector_type(4))) __bf16 bf16x4;
typedef __attribute__((ext_vector_type(4))) float f32x4;

#define MFMA(a, b, c) __builtin_amdgcn_mfma_f32_16x16x32_bf16((a), (b), (c), 0, 0, 0)

__device__ __forceinline__ void gl2lds16(const __bf16* g, __bf16* l) {
  __builtin_amdgcn_global_load_lds(
      (const __attribute__((address_space(1))) void*)(const void*)g,
      (__attribute__((address_space(3))) void*)(void*)l, 16, 0, 0);
}

// Self-detect: sample x's first 64 dwords (uniform scalar loads). fp32 data's
// low halfwords are mantissa bytes -> exponent field >= 0xC0 w.p. ~1/4; real
// bf16 N(0,1)-scale data never has exp >= 0xC0.
__device__ __forceinline__ int detect_f32(const unsigned int* __restrict__ xw) {
  int c = 0;
#pragma unroll
  for (int i = 0; i < 64; ++i) {
    const unsigned int u = xw[i];
    c += (((u >> 7) & 0xFF) >= 0xC0) ? 1 : 0;
    c += (((u >> 23) & 0xFF) >= 0xC0) ? 1 : 0;
  }
  return c > 8;
}

// ---------------- K0a: canonicalize x ----------------------------------------
__global__ __launch_bounds__(256) void k_convert_x(const void* __restrict__ src,
                                                   __bf16* __restrict__ dst) {
  const int i = (blockIdx.x * 256 + threadIdx.x) * 8;  // < 16777216
  if (detect_f32((const unsigned int*)src)) {
    const float* s = (const float*)src;
    bf16x8 v;
#pragma unroll
    for (int j = 0; j < 8; ++j) v[j] = (__bf16)s[i + j];
    *(bf16x8*)(dst + i) = v;
  } else {
    *(bf16x8*)(dst + i) = *(const bf16x8*)((const __bf16*)src + i);
  }
}

// ---------------- K0b: canonicalize the 11 weight/bias/temp inputs -----------
__global__ __launch_bounds__(256) void k_convert_w(
    const void* s0, const void* s1, const void* s2, const void* s3, const void* s4,
    const void* s5, const void* s6, const void* s7, const void* s8, const void* s9,
    const void* s10, __bf16* __restrict__ cw, const void* __restrict__ xsrc) {
  const int i = (blockIdx.x * 256 + threadIdx.x) * 8;
  if (i >= 1376656) return;
  const void* s;
  int base;
  if (i < 262144)        { s = s0;  base = 0; }
  else if (i < 786432)   { s = s1;  base = 262144; }
  else if (i < 786496)   { s = s2;  base = 786432; }
  else if (i < 1310784)  { s = s3;  base = 786496; }
  else if (i < 1310848)  { s = s4;  base = 1310784; }
  else if (i < 1343616)  { s = s5;  base = 1310848; }
  else if (i < 1343744)  { s = s6;  base = 1343616; }
  else if (i < 1376512)  { s = s7;  base = 1343744; }
  else if (i < 1376640)  { s = s8;  base = 1376512; }
  else if (i < 1376648)  { s = s9;  base = 1376640; }
  else                   { s = s10; base = 1376648; }
  const int li = i - base;
  if (detect_f32((const unsigned int*)xsrc)) {
    const float* sf = (const float*)s;
#pragma unroll
    for (int j = 0; j < 8; ++j) cw[i + j] = (__bf16)sf[li + j];
  } else {
    const __bf16* sb = (const __bf16*)s;
#pragma unroll
    for (int j = 0; j < 8; ++j) cw[i + j] = sb[li + j];
  }
}

// ---------------- K1: qkvv = x @ Wqkvv^T (dbuf pipeline, transposed store) ---
__global__ __launch_bounds__(256) void k_qkvv(const __bf16* __restrict__ x,
                                              const __bf16* __restrict__ Wq,
                                              __bf16* __restrict__ qkvv,
                                              float* __restrict__ npart) {
  __shared__ alignas(16) __bf16 As[2][128 * 32];
  __shared__ alignas(16) __bf16 Bs[2][128 * 32];
  __shared__ alignas(16) __bf16 Cs[32 * 136];  // transpose tile, padded stride
  const int t = threadIdx.x, lane = t & 63;
  const int wr = t >> 7, wc = (t >> 6) & 1;
  const int l15 = lane & 15, g = lane >> 4;
  const int f0 = blockIdx.y * 128;
  const int t0 = blockIdx.x * 128;
  f32x4 acc[4][4] = {};
  const int r = t >> 2;
  const int c8 = ((t & 3) ^ ((t >> 3) & 3)) * 8;  // staged (swizzled) chunk
  const int cx = ((g ^ ((l15 >> 1) & 3)) * 8);    // read-side chunk
  // prologue: stage k-step 0 into buffer 0
#pragma unroll
  for (int i = 0; i < 2; ++i) {
    gl2lds16(Wq + (size_t)(f0 + i * 64 + r) * 256 + c8, &As[0][i * 2048 + t * 8]);
    gl2lds16(x + (size_t)(t0 + i * 64 + r) * 256 + c8, &Bs[0][i * 2048 + t * 8]);
  }
  __syncthreads();
  for (int ks = 0; ks < 8; ++ks) {
    const int cur = ks & 1, nxt = cur ^ 1;
    if (ks < 7) {  // issue next-step stage BEFORE this step's compute
      const int k1 = (ks + 1) * 32;
#pragma unroll
      for (int i = 0; i < 2; ++i) {
        gl2lds16(Wq + (size_t)(f0 + i * 64 + r) * 256 + k1 + c8, &As[nxt][i * 2048 + t * 8]);
        gl2lds16(x + (size_t)(t0 + i * 64 + r) * 256 + k1 + c8, &Bs[nxt][i * 2048 + t * 8]);
      }
    }
    bf16x8 af[4], bfr[4];
#pragma unroll
    for (int i = 0; i < 4; ++i) {
      af[i] = *(const bf16x8*)(&As[cur][(wr * 64 + i * 16 + l15) * 32 + cx]);
      bfr[i] = *(const bf16x8*)(&Bs[cur][(wc * 64 + i * 16 + l15) * 32 + cx]);
    }
#pragma unroll
    for (int i = 0; i < 4; ++i)
#pragma unroll
      for (int j = 0; j < 4; ++j) acc[i][j] = MFMA(af[i], bfr[j], acc[i][j]);
    __syncthreads();  // drains prefetch (nxt ready) + protects cur for reuse
  }
  const int b = t0 >> 13;
  const int n0 = t0 & 8191;
  // Epilogue: per 32-f slab, stage to LDS, emit 256B-dense row stores + norm partials.
  for (int i = 0; i < 4; ++i) {
    if (i) __syncthreads();  // protect Cs from previous iteration's readers
#pragma unroll
    for (int j = 0; j < 4; ++j)
#pragma unroll
      for (int rr = 0; rr < 4; ++rr)
        Cs[(wr * 16 + g * 4 + rr) * 136 + wc * 64 + j * 16 + l15] = (__bf16)acc[i][j][rr];
    __syncthreads();
#pragma unroll
    for (int half = 0; half < 2; ++half) {
      const int row_l = (t >> 4) + half * 16;     // [0,32): 16 threads per row
      const int col8 = (t & 15) * 8;              // [0,128) in steps of 8
      const bf16x8 v = *(const bf16x8*)(Cs + row_l * 136 + col8);
      const int f = f0 + (row_l >> 4) * 64 + i * 16 + (row_l & 15);
      *(bf16x8*)(qkvv + (size_t)(((f >> 8) * 8 + b) * 256 + (f & 255)) * 8192 + n0 + col8) = v;
      if (f0 < 512) {  // q (f<256) and k (256<=f<512) L2-norm partial sums
        float s = 0.f;
#pragma unroll
        for (int jj = 0; jj < 8; ++jj) { const float q = (float)v[jj]; s += q * q; }
#pragma unroll
        for (int off = 1; off < 16; off <<= 1) s += __shfl_xor(s, off, 16);
        if ((t & 15) == 0) npart[(size_t)blockIdx.x * 512 + f] = s;
      }
    }
  }
}

// ---------------- K1b: reduce norm partials over the 64 token-blocks of each b
__global__ __launch_bounds__(256) void k_nred(const float* __restrict__ npart,
                                              float* __restrict__ qsum,
                                              float* __restrict__ ksum) {
  const int which = blockIdx.x >> 3, b = blockIdx.x & 7;
  const int c = threadIdx.x;
  float s = 0.f;
#pragma unroll 4
  for (int j = 0; j < 64; ++j)
    s += npart[(size_t)(b * 64 + j) * 512 + which * 256 + c];
  (which ? ksum : qsum)[b * 256 + c] = s;
}

// ---------------- K3: k_proj / v_proj partial GEMMs (K-split, dbuf) ----------
__global__ __launch_bounds__(256) void k_proj_part(const __bf16* __restrict__ qkvv,
                                                   const __bf16* __restrict__ WE,
                                                   const __bf16* __restrict__ WF,
                                                   float* __restrict__ pbuf) {
  __shared__ alignas(16) __bf16 As[2][128 * 32];
  __shared__ alignas(16) __bf16 Bs[2][64 * 32];
  const int t = threadIdx.x, lane = t & 63;
  const int wr = t >> 7, wc = (t >> 6) & 1;
  const int l15 = lane & 15, g = lane >> 4;
  const int kc = blockIdx.x, mt = blockIdx.y, pj = blockIdx.z;
  const __bf16* A = qkvv + (size_t)(pj ? 3 : 1) * 2048 * 8192;
  const __bf16* Bm = pj ? WF : WE;
  const int r0 = mt * 128;
  f32x4 acc[4][2] = {};
  const int r = t >> 2;
  const int c8 = ((t & 3) ^ ((t >> 3) & 3)) * 8;
  const int cx = ((g ^ ((l15 >> 1) & 3)) * 8);
  const int kb = kc * 512;
  // prologue
#pragma unroll
  for (int i = 0; i < 2; ++i)
    gl2lds16(A + (size_t)(r0 + i * 64 + r) * 8192 + kb + c8, &As[0][i * 2048 + t * 8]);
  gl2lds16(Bm + (size_t)r * 8192 + kb + c8, &Bs[0][t * 8]);
  __syncthreads();
  for (int ks = 0; ks < 16; ++ks) {
    const int cur = ks & 1, nxt = cur ^ 1;
    if (ks < 15) {
      const int k1 = kb + (ks + 1) * 32;
#pragma unroll
      for (int i = 0; i < 2; ++i)
        gl2lds16(A + (size_t)(r0 + i * 64 + r) * 8192 + k1 + c8, &As[nxt][i * 2048 + t * 8]);
      gl2lds16(Bm + (size_t)r * 8192 + k1 + c8, &Bs[nxt][t * 8]);
    }
    bf16x8 af[4], bfr[2];
#pragma unroll
    for (int i = 0; i < 4; ++i)
      af[i] = *(const bf16x8*)(&As[cur][(wr * 64 + i * 16 + l15) * 32 + cx]);
#pragma unroll
    for (int j = 0; j < 2; ++j)
      bfr[j] = *(const bf16x8*)(&Bs[cur][(wc * 32 + j * 16 + l15) * 32 + cx]);
#pragma unroll
    for (int i = 0; i < 4; ++i)
#pragma unroll
      for (int j = 0; j < 2; ++j) acc[i][j] = MFMA(af[i], bfr[j], acc[i][j]);
    __syncthreads();
  }
  float* dst = pbuf + (size_t)((pj * 16 + kc) * 2048 + r0) * 64;
#pragma unroll
  for (int i = 0; i < 4; ++i)
#pragma unroll
    for (int j = 0; j < 2; ++j)
#pragma unroll
      for (int rr = 0; rr < 4; ++rr)
        dst[(wr * 64 + i * 16 + g * 4 + rr) * 64 + wc * 32 + j * 16 + l15] = acc[i][j][rr];
}

// ---------------- K3b: reduce + bias; emit bf16 MFMA-operand copies ----------
__global__ __launch_bounds__(256) void k_proj_reduce(const float* __restrict__ pbuf,
                                                     const __bf16* __restrict__ bE,
                                                     const __bf16* __restrict__ bF,
                                                     const float* __restrict__ qsum,
                                                     const __bf16* __restrict__ t2,
                                                     __bf16* __restrict__ kprojT,
                                                     __bf16* __restrict__ vprojb) {
  const int idx = blockIdx.x * 256 + threadIdx.x;  // [0, 262144)
  const int pj = idx >> 17, rp = idx & 131071, p = idx & 63;
  const int row = rp >> 6, bh = row >> 5, d = row & 31, h = bh & 7;
  float s = (float)((pj ? bF : bE)[p]);
  const float* src = pbuf + (size_t)pj * 16 * 131072 + rp;
#pragma unroll
  for (int k = 0; k < 16; ++k) s += src[(size_t)k * 131072];
  if (pj == 0) {
    const float qi = 1.0f / fmaxf(sqrtf(qsum[row]), 1e-12f);
    kprojT[bh * 2048 + p * 32 + d] = (__bf16)(s * qi * (float)t2[h]);
  } else {
    vprojb[bh * 2048 + d * 64 + p] = (__bf16)s;
  }
}

// ---------------- K4a: S[d,e] = q . k partials (K-split 8 x 4 waves) ---------
__global__ __launch_bounds__(256) void k_sca_part(const __bf16* __restrict__ qkvv,
                                                  float* __restrict__ spart) {
  const int bh = blockIdx.x, kc = blockIdx.y;
  const int t = threadIdx.x, lane = t & 63, w = t >> 6;
  const __bf16* qb = qkvv + (size_t)(bh * 32) * 8192;
  const __bf16* kb = qkvv + (size_t)(2048 + bh * 32) * 8192;
  f32x4 acc[2][2] = {};
  const int kbase = kc * 1024 + w * 256 + (lane >> 4) * 8;
#pragma unroll
  for (int ks = 0; ks < 256; ks += 32) {
    bf16x8 af[2], bfr[2];
#pragma unroll
    for (int i = 0; i < 2; ++i) {
      af[i] = *(const bf16x8*)(qb + (size_t)(i * 16 + (lane & 15)) * 8192 + kbase + ks);
      bfr[i] = *(const bf16x8*)(kb + (size_t)(i * 16 + (lane & 15)) * 8192 + kbase + ks);
    }
#pragma unroll
    for (int i = 0; i < 2; ++i)
#pragma unroll
      for (int j = 0; j < 2; ++j) acc[i][j] = MFMA(af[i], bfr[j], acc[i][j]);
  }
  float* dst = spart + (size_t)((bh * 8 + kc) * 4 + w) * 1024;
#pragma unroll
  for (int i = 0; i < 2; ++i)
#pragma unroll
    for (int j = 0; j < 2; ++j)
#pragma unroll
      for (int rr = 0; rr < 4; ++rr)
        dst[(i * 16 + (lane >> 4) * 4 + rr) * 32 + j * 16 + (lane & 15)] = acc[i][j][rr];
}

// ---------------- K4b: reduce, scale, softmax over e; emit bf16 attn [d][e] --
__global__ __launch_bounds__(256) void k_sca_softmax(const float* __restrict__ spart,
                                                     const float* __restrict__ qsum,
                                                     const float* __restrict__ ksum,
                                                     const __bf16* __restrict__ temp1,
                                                     __bf16* __restrict__ attnb) {
  const int bh = blockIdx.x;
  __shared__ float S[1024];
  const int t = threadIdx.x;
  const float tmp = (float)temp1[bh & 7];
  for (int idx = t; idx < 1024; idx += 256) {
    float s = 0.f;
    const float* src = spart + (size_t)bh * 32768 + idx;
#pragma unroll
    for (int k = 0; k < 32; ++k) s += src[k * 1024];
    const float qi = 1.0f / fmaxf(sqrtf(qsum[bh * 32 + (idx >> 5)]), 1e-12f);
    const float ki = 1.0f / fmaxf(sqrtf(ksum[bh * 32 + (idx & 31)]), 1e-12f);
    S[idx] = s * qi * ki * tmp;
  }
  __syncthreads();
  const int lane = t & 63, w = t >> 6;
#pragma unroll
  for (int rr = 0; rr < 4; ++rr) {
    const int row = rr * 8 + w * 2 + (lane >> 5);
    const int e = lane & 31;
    float v = S[row * 32 + e];
    float m = v;
#pragma unroll
    for (int off = 16; off; off >>= 1) m = fmaxf(m, __shfl_xor(m, off, 32));
    const float ex = __expf(v - m);
    float sm = ex;
#pragma unroll
    for (int off = 16; off; off >>= 1) sm += __shfl_xor(sm, off, 32);
    attnb[(size_t)bh * 1024 + row * 32 + e] = (__bf16)(ex / sm);
  }
}

// ---------------- K4c/K5 merged: channel-attn apply + spatial attention ------
__global__ __launch_bounds__(256) void k_casa(const __bf16* __restrict__ qkvv,
                                              const __bf16* __restrict__ attnb,
                                              const __bf16* __restrict__ kprojT,
                                              const __bf16* __restrict__ vprojb,
                                              __bf16* __restrict__ xca,
                                              __bf16* __restrict__ xsa) {
  __shared__ __bf16 P[4][16 * 72];  // used by the sa branch only
  const int t = threadIdx.x, lane = t & 63, w = t >> 6;
  const int l15 = lane & 15, g = lane >> 4;
  if (blockIdx.y < 64) {
    // ---- channel attention: x_ca[d][tok] = sum_e attn[d][e] * v_ca[e][tok]
    const int bh = blockIdx.y, b = bh >> 3, h = bh & 7;
    const __bf16* vb = qkvv + (size_t)(4096 + bh * 32) * 8192;
    bf16x8 aa[2];
#pragma unroll
    for (int mi = 0; mi < 2; ++mi)
      aa[mi] = *(const bf16x8*)(attnb + bh * 1024 + (mi * 16 + l15) * 32 + g * 8);
#pragma unroll
    for (int it = 0; it < 4; ++it) {
      const int n = blockIdx.x * 256 + it * 64 + w * 16 + l15;
      union { bf16x8 v; unsigned short u[8]; } bq;
#pragma unroll
      for (int j = 0; j < 8; ++j)
        bq.u[j] = *(const unsigned short*)(vb + (size_t)(g * 8 + j) * 8192 + n);
      f32x4 o[2] = {};
#pragma unroll
      for (int mi = 0; mi < 2; ++mi) o[mi] = MFMA(aa[mi], bq.v, o[mi]);
#pragma unroll
      for (int mi = 0; mi < 2; ++mi) {
        bf16x4 p4;
#pragma unroll
        for (int rr = 0; rr < 4; ++rr) p4[rr] = (__bf16)o[mi][rr];
        *(bf16x4*)(xca + (size_t)(b * 8192 + n) * 256 + h * 32 + mi * 16 + g * 4) = p4;
      }
    }
  } else {
    // ---- spatial (low-rank) attention
    const int bh = blockIdx.y - 64;
    const __bf16* qb = qkvv + (size_t)(bh * 32) * 8192;
    bf16x8 ka[4], va[2][2];
#pragma unroll
    for (int tile = 0; tile < 4; ++tile)
      ka[tile] = *(const bf16x8*)(kprojT + bh * 2048 + (tile * 16 + l15) * 32 + g * 8);
#pragma unroll
    for (int mi = 0; mi < 2; ++mi)
#pragma unroll
      for (int kh = 0; kh < 2; ++kh)
        va[mi][kh] = *(const bf16x8*)(vprojb + bh * 2048 + (mi * 16 + l15) * 64 + kh * 32 + g * 8);
    __bf16* Pw = &P[w][0];
#pragma unroll
    for (int it = 0; it < 4; ++it) {
      const int n0 = blockIdx.x * 256 + it * 64 + w * 16;
      union { bf16x8 v; unsigned short u[8]; } bq;
#pragma unroll
      for (int j = 0; j < 8; ++j)
        bq.u[j] = *(const unsigned short*)(qb + (size_t)(g * 8 + j) * 8192 + n0 + l15);
      f32x4 st[4];
#pragma unroll
      for (int tile = 0; tile < 4; ++tile) {
        f32x4 z = {};
        st[tile] = MFMA(ka[tile], bq.v, z);
      }
      float m = st[0][0];
#pragma unroll
      for (int tile = 0; tile < 4; ++tile)
#pragma unroll
        for (int rr = 0; rr < 4; ++rr) m = fmaxf(m, st[tile][rr]);
      m = fmaxf(m, __shfl_xor(m, 16, 64));
      m = fmaxf(m, __shfl_xor(m, 32, 64));
      float sum = 0.f;
#pragma unroll
      for (int tile = 0; tile < 4; ++tile) {
        bf16x4 p4;
#pragma unroll
        for (int rr = 0; rr < 4; ++rr) {
          const float ex = __expf(st[tile][rr] - m);
          sum += ex;
          p4[rr] = (__bf16)ex;
        }
        *(bf16x4*)(Pw + l15 * 72 + tile * 16 + g * 4) = p4;
      }
      sum += __shfl_xor(sum, 16, 64);
      sum += __shfl_xor(sum, 32, 64);
      const float inv = 1.0f / sum;
      f32x4 o[2] = {};
#pragma unroll
      for (int kh = 0; kh < 2; ++kh) {
        const bf16x8 pf = *(const bf16x8*)(Pw + l15 * 72 + kh * 32 + g * 8);
#pragma unroll
        for (int mi = 0; mi < 2; ++mi) o[mi] = MFMA(va[mi][kh], pf, o[mi]);
      }
#pragma unroll
      for (int mi = 0; mi < 2; ++mi)
#pragma unroll
        for (int rr = 0; rr < 4; ++rr) {
          const int d = mi * 16 + g * 4 + rr;
          xsa[(size_t)(bh * 32 + d) * 8192 + n0 + l15] = (__bf16)(o[mi][rr] * inv);
        }
    }
  }
}

// ---------------- K6: output projections (both halves, dbuf) -----------------
__global__ __launch_bounds__(256) void k_out(const __bf16* __restrict__ xsa,
                                             const __bf16* __restrict__ xca,
                                             const __bf16* __restrict__ Wo1,
                                             const __bf16* __restrict__ bo1,
                                             const __bf16* __restrict__ Wo2,
                                             const __bf16* __restrict__ bo2,
                                             void* __restrict__ outv,
                                             const void* __restrict__ xsrc) {
  __shared__ alignas(16) __bf16 As[2][128 * 32];
  __shared__ alignas(16) __bf16 Bs[2][128 * 32];
  const int t = threadIdx.x, lane = t & 63;
  const int wr = t >> 7, wc = (t >> 6) & 1;
  const int l15 = lane & 15, g = lane >> 4;
  const int nt = blockIdx.x, b = blockIdx.y, br = blockIdx.z;
  const int isf32 = detect_f32((const unsigned int*)xsrc);
  const __bf16* Wo = br ? Wo2 : Wo1;
  const __bf16* bo = br ? bo2 : bo1;
  f32x4 acc[4][4] = {};
  const int r = t >> 2;
  const int c8 = ((t & 3) ^ ((t >> 3) & 3)) * 8;
  const int cx = ((g ^ ((l15 >> 1) & 3)) * 8);
  const int row_b = nt * 128 + r;
  // A-source addresses for row (nt*128 + i*64 + r) at column k0+c8
  auto asrc = [&](int i, int k0) -> const __bf16* {
    const int row = row_b + i * 64;
    if (br == 0)
      return xsa + (size_t)((b * 8 + ((row >> 5) & 7)) * 32 + (row >> 8)) * 8192 +
             (row & 31) * 256 + k0 + c8;
    return xca + (size_t)(b * 8192 + row) * 256 + k0 + c8;
  };
  // prologue
#pragma unroll
  for (int i = 0; i < 2; ++i) {
    gl2lds16(asrc(i, 0), &As[0][i * 2048 + t * 8]);
    gl2lds16(Wo + (size_t)(i * 64 + r) * 256 + c8, &Bs[0][i * 2048 + t * 8]);
  }
  __syncthreads();
  for (int ks = 0; ks < 8; ++ks) {
    const int cur = ks & 1, nxt = cur ^ 1;
    if (ks < 7) {
      const int k1 = (ks + 1) * 32;
#pragma unroll
      for (int i = 0; i < 2; ++i) {
        gl2lds16(asrc(i, k1), &As[nxt][i * 2048 + t * 8]);
        gl2lds16(Wo + (size_t)(i * 64 + r) * 256 + k1 + c8, &Bs[nxt][i * 2048 + t * 8]);
      }
    }
    bf16x8 af[4], bfr[4];
#pragma unroll
    for (int i = 0; i < 4; ++i) {
      af[i] = *(const bf16x8*)(&As[cur][(wr * 64 + i * 16 + l15) * 32 + cx]);
      bfr[i] = *(const bf16x8*)(&Bs[cur][(wc * 64 + i * 16 + l15) * 32 + cx]);
    }
#pragma unroll
    for (int i = 0; i < 4; ++i)
#pragma unroll
      for (int j = 0; j < 4; ++j) acc[i][j] = MFMA(af[i], bfr[j], acc[i][j]);
    __syncthreads();
  }
  float bias[4];
#pragma unroll
  for (int j = 0; j < 4; ++j) bias[j] = (float)bo[wc * 64 + j * 16 + l15];
#pragma unroll
  for (int i = 0; i < 4; ++i) {
#pragma unroll
    for (int j = 0; j < 4; ++j) {
      const int col = wc * 64 + j * 16 + l15;
#pragma unroll
      for (int rr = 0; rr < 4; ++rr) {
        const int row = nt * 128 + wr * 64 + i * 16 + g * 4 + rr;
        const float val = acc[i][j][rr] + bias[j];
        const size_t oi = (size_t)(b * 8192 + row) * 256 + br * 128 + col;
        if (isf32) ((float*)outv)[oi] = val;
        else ((__bf16*)outv)[oi] = (__bf16)val;
      }
    }
  }
}

extern "C" void kernel_launch(void* const* d_in, const int* in_sizes, int n_in,
                              void* d_out, int out_size, void* d_ws, size_t ws_size,
                              hipStream_t stream) {
  char* ws = (char*)d_ws;
  __bf16* qkvv   = (__bf16*)(ws);                    // 134,217,728 B
  __bf16* cinx   = (__bf16*)(ws + 134217728ull);     //  32 MB (region A)
  __bf16* xca    = (__bf16*)(ws + 134217728ull);     //  alias A (cinx dead after k_qkvv)
  float*  pbuf   = (float*)(ws + 167772160ull);      //  16 MB (region B)
  float*  npart  = (float*)(ws + 184549376ull);      //   1 MB (region C; dead after k_nred)
  float*  spart  = (float*)(ws + 184549376ull);      //   8 MB (alias C, written later)
  __bf16* xsa    = (__bf16*)(ws + 167772160ull);     //  alias B (pbuf/spart dead by then)
  __bf16* kprojT = (__bf16*)(ws + 201326592ull);     //  262,144 B
  __bf16* vprojb = (__bf16*)(ws + 201588736ull);     //  262,144 B
  float*  qsum   = (float*)(ws + 201850880ull);      //    8,192 B
  float*  ksum   = (float*)(ws + 201859072ull);      //    8,192 B
  __bf16* attnb  = (__bf16*)(ws + 201867264ull);     //  131,072 B
  __bf16* cw     = (__bf16*)(ws + 201998336ull);     //  2,753,536 B

  __bf16* cWq  = cw;
  __bf16* cWE  = cw + 262144;
  __bf16* cbE  = cw + 786432;
  __bf16* cWF  = cw + 786496;
  __bf16* cbF  = cw + 1310784;
  __bf16* cWo1 = cw + 1310848;
  __bf16* cbo1 = cw + 1343616;
  __bf16* cWo2 = cw + 1343744;
  __bf16* cbo2 = cw + 1376512;
  __bf16* ct1  = cw + 1376640;
  __bf16* ct2  = cw + 1376648;

  k_convert_x<<<8192, 256, 0, stream>>>(d_in[0], cinx);
  k_convert_w<<<673, 256, 0, stream>>>(d_in[1], d_in[2], d_in[3], d_in[4], d_in[5],
                                       d_in[6], d_in[7], d_in[8], d_in[9], d_in[10],
                                       d_in[11], cw, d_in[0]);
  k_qkvv<<<dim3(512, 8), 256, 0, stream>>>(cinx, cWq, qkvv, npart);
  k_nred<<<16, 256, 0, stream>>>(npart, qsum, ksum);
  k_proj_part<<<dim3(16, 16, 2), 256, 0, stream>>>(qkvv, cWE, cWF, pbuf);
  k_proj_reduce<<<dim3(1024), 256, 0, stream>>>(pbuf, cbE, cbF, qsum, ct2, kprojT, vprojb);
  k_sca_part<<<dim3(64, 8), 256, 0, stream>>>(qkvv, spart);
  k_sca_softmax<<<dim3(64), 256, 0, stream>>>(spart, qsum, ksum, ct1, attnb);
  k_casa<<<dim3(32, 128), 256, 0, stream>>>(qkvv, attnb, kprojT, vprojb, xca, xsa);
  k_out<<<dim3(64, 8, 2), 256, 0, stream>>>(xsa, xca, cWo1, cbo1, cWo2, cbo2, d_out, d_in[0]);
}